// Round 1
// baseline (1724.326 us; speedup 1.0000x reference)
//
#include <hip/hip_runtime.h>
#include <math.h>

// Fused GN + self-attention block, fp32 baseline (round 0).
// Workspace layout (floats):
//   qkv   : [B][3C][N]  = 12,582,912
//   obuf  : [B][C][N]   =  4,194,304
//   stats : [B*G][2]    =         64   (mean, rstd)
//   ascale: [B][C]      =       1024   (rstd * gn_weight)
//   bias2 : [B][3C]     =       3072   (qkv_b + W @ (gn_bias - mean*ascale); q-part pre-scaled by 1/16)
// total = 16,781,376 floats = 67,125,504 bytes required of ws_size.

#define BATCH 4
#define CH 256
#define NSP 4096
#define NGRP 8
#define CPG 32
#define QT 32
#define KT 64

// ---------------- kernel 1: GroupNorm statistics ----------------
__global__ __launch_bounds__(256) void gn_stats_k(const float* __restrict__ x,
                                                  float* __restrict__ stats) {
  const int bg = blockIdx.x;  // b*8+g ; group data is contiguous 32*4096 floats
  const float4* p = (const float4*)(x + (size_t)bg * CPG * NSP);
  const int t = threadIdx.x;
  float s1 = 0.f, s2 = 0.f;
  for (int i = t; i < CPG * NSP / 4; i += 256) {
    float4 v = p[i];
    s1 += v.x + v.y + v.z + v.w;
    s2 += v.x * v.x + v.y * v.y + v.z * v.z + v.w * v.w;
  }
  __shared__ float r1[256], r2[256];
  r1[t] = s1; r2[t] = s2;
  __syncthreads();
  for (int off = 128; off > 0; off >>= 1) {
    if (t < off) { r1[t] += r1[t + off]; r2[t] += r2[t + off]; }
    __syncthreads();
  }
  if (t == 0) {
    const float inv = 1.f / (float)(CPG * NSP);
    const float mean = r1[0] * inv;
    const float var = r2[0] * inv - mean * mean;
    stats[bg * 2] = mean;
    stats[bg * 2 + 1] = rsqrtf(var + 1e-5f);
  }
}

// ---------------- kernel 2: fold GN affine into GEMM scale/bias ----------------
__global__ __launch_bounds__(256) void fold_k(const float* __restrict__ gn_w,
                                              const float* __restrict__ gn_b,
                                              const float* __restrict__ qkv_w,
                                              const float* __restrict__ qkv_b,
                                              const float* __restrict__ stats,
                                              float* __restrict__ ascale,
                                              float* __restrict__ bias2) {
  const int b = blockIdx.x;   // 4 blocks, 256 threads
  const int t = threadIdx.x;
  __shared__ float bb[CH];
  {
    const int c = t;
    const int g = c / CPG;
    const float mean = stats[(b * NGRP + g) * 2];
    const float rstd = stats[(b * NGRP + g) * 2 + 1];
    const float a = rstd * gn_w[c];
    ascale[b * CH + c] = a;
    bb[c] = gn_b[c] - mean * a;
  }
  __syncthreads();
  for (int o = t; o < 3 * CH; o += 256) {
    const float* wrow = qkv_w + (size_t)o * CH;
    float acc = qkv_b[o];
    for (int c = 0; c < CH; ++c) acc += wrow[c] * bb[c];
    if (o < CH) acc *= 0.0625f;             // fold 1/sqrt(C) into q
    bias2[b * 3 * CH + o] = acc;
  }
}

// ---------------- kernel 3: QKV GEMM (GN applied on the fly) ----------------
// qkv[b][o][n] = qscale * sum_c w[o][c]*ascale[b][c]*x[b][c][n] + bias2[b][o]
__global__ __launch_bounds__(256) void qkv_gemm_k(const float* __restrict__ x,
                                                  const float* __restrict__ qkv_w,
                                                  const float* __restrict__ ascale,
                                                  const float* __restrict__ bias2,
                                                  float* __restrict__ qkv) {
  const int b = blockIdx.z;
  const int ob = blockIdx.y * 64;
  const int nb = blockIdx.x * 64;
  const int t = threadIdx.x;
  __shared__ float As[16][68];   // [k][o], padded
  __shared__ float Bs[16][64];   // [k][n]
  float acc[4][4] = {};
  const int to = (t & 15) * 4;
  const int tn = (t >> 4) * 4;
  const float* xb = x + (size_t)b * CH * NSP;
  for (int kc = 0; kc < CH; kc += 16) {
    __syncthreads();
    {
      const int o = t >> 2, k4 = (t & 3) * 4;
      const float4 w4 = *(const float4*)(qkv_w + (size_t)(ob + o) * CH + kc + k4);
      As[k4 + 0][o] = w4.x; As[k4 + 1][o] = w4.y;
      As[k4 + 2][o] = w4.z; As[k4 + 3][o] = w4.w;
    }
    {
      const int k = t >> 4, n4 = (t & 15) * 4;
      float4 v = *(const float4*)(xb + (size_t)(kc + k) * NSP + nb + n4);
      const float a = ascale[b * CH + kc + k];
      v.x *= a; v.y *= a; v.z *= a; v.w *= a;
      *(float4*)&Bs[k][n4] = v;
    }
    __syncthreads();
#pragma unroll
    for (int k = 0; k < 16; ++k) {
      const float4 a4 = *(const float4*)&As[k][to];
      const float4 b4 = *(const float4*)&Bs[k][tn];
      const float av[4] = {a4.x, a4.y, a4.z, a4.w};
      const float bv[4] = {b4.x, b4.y, b4.z, b4.w};
#pragma unroll
      for (int i = 0; i < 4; ++i)
#pragma unroll
        for (int j = 0; j < 4; ++j) acc[i][j] += av[i] * bv[j];
    }
  }
  const float qscale = (ob < CH) ? 0.0625f : 1.0f;
#pragma unroll
  for (int i = 0; i < 4; ++i) {
    const int o = ob + to + i;
    const float bias = bias2[b * 3 * CH + o];
    float4 r;
    r.x = acc[i][0] * qscale + bias;
    r.y = acc[i][1] * qscale + bias;
    r.z = acc[i][2] * qscale + bias;
    r.w = acc[i][3] * qscale + bias;
    *(float4*)(qkv + ((size_t)(b * 3 * CH + o)) * NSP + nb + tn) = r;
  }
}

// ---------------- kernel 4: flash attention ----------------
// Per block: 32 queries, loop over 64-wide key tiles with online softmax.
__global__ __launch_bounds__(256) void attn_k(const float* __restrict__ qkv,
                                              float* __restrict__ obuf) {
  const int b = blockIdx.y;
  const int qb = blockIdx.x * QT;
  const int t = threadIdx.x;

  const float* Qp = qkv + (size_t)b * 3 * CH * NSP;          // pre-scaled by 1/16
  const float* Kp = Qp + (size_t)CH * NSP;
  const float* Vp = Kp + (size_t)CH * NSP;

  __shared__ float Qs[CH][QT];     // 32 KB  [c][q]
  __shared__ float Ks[64][KT];     // 16 KB  [c-chunk][k]
  __shared__ float Ps[KT][33];     //  8.25 KB  [k][q], padded
  __shared__ float Vs[64][65];     // 16.25 KB  [c-chunk][k], padded
  __shared__ float mS[QT], lS[QT], aS[QT];

  // load Q tile [256][32]
  for (int f = t; f < CH * QT / 4; f += 256) {
    const int c = f >> 3;
    const int q4 = (f & 7) << 2;
    const float4 v = *(const float4*)(Qp + (size_t)c * NSP + qb + q4);
    Qs[c][q4] = v.x; Qs[c][q4 + 1] = v.y; Qs[c][q4 + 2] = v.z; Qs[c][q4 + 3] = v.w;
  }
  if (t < QT) { mS[t] = -INFINITY; lS[t] = 0.f; }

  const int qg = t >> 5;          // 0..7  : QK rows q0..q0+3
  const int kg = t & 31;          //       : QK cols k0,k0+1
  const int q0 = qg << 2;
  const int k0 = kg << 1;
  const int pq = t & 15;          // PV rows 2*pq, 2*pq+1
  const int pc = t >> 4;          // PV cols 4*pc within 64-chunk

  float oacc[4][2][4];
#pragma unroll
  for (int a = 0; a < 4; ++a)
#pragma unroll
    for (int i = 0; i < 2; ++i)
#pragma unroll
      for (int j = 0; j < 4; ++j) oacc[a][i][j] = 0.f;

  for (int kt = 0; kt < NSP; kt += KT) {
    // ---- S = Q^T K over c in chunks of 64 ----
    float s[4][2] = {{0.f, 0.f}, {0.f, 0.f}, {0.f, 0.f}, {0.f, 0.f}};
    for (int cc = 0; cc < CH; cc += 64) {
      __syncthreads();
#pragma unroll
      for (int i = 0; i < 4; ++i) {
        const int f = t + 256 * i;            // float4 index over [64][16]
        const int c = f >> 4;
        const int k4 = (f & 15) << 2;
        *(float4*)&Ks[c][k4] = *(const float4*)(Kp + (size_t)(cc + c) * NSP + kt + k4);
      }
      __syncthreads();
#pragma unroll 4
      for (int c = 0; c < 64; ++c) {
        const float4 qv = *(const float4*)&Qs[cc + c][q0];
        const float2 kv = *(const float2*)&Ks[c][k0];
        s[0][0] += qv.x * kv.x; s[0][1] += qv.x * kv.y;
        s[1][0] += qv.y * kv.x; s[1][1] += qv.y * kv.y;
        s[2][0] += qv.z * kv.x; s[2][1] += qv.z * kv.y;
        s[3][0] += qv.w * kv.x; s[3][1] += qv.w * kv.y;
      }
    }
    // ---- online softmax; row q0+i lives in 32 consecutive lanes (kg) ----
#pragma unroll
    for (int i = 0; i < 4; ++i) {
      float mx = fmaxf(s[i][0], s[i][1]);
#pragma unroll
      for (int d = 1; d < 32; d <<= 1) mx = fmaxf(mx, __shfl_xor(mx, d));
      const float mold = mS[q0 + i];
      const float mnew = fmaxf(mold, mx);
      const float p0 = __expf(s[i][0] - mnew);
      const float p1 = __expf(s[i][1] - mnew);
      Ps[k0][q0 + i] = p0;
      Ps[k0 + 1][q0 + i] = p1;
      float sum = p0 + p1;
#pragma unroll
      for (int d = 1; d < 32; d <<= 1) sum += __shfl_xor(sum, d);
      if (kg == 0) {
        const float alpha = __expf(mold - mnew);
        aS[q0 + i] = alpha;
        mS[q0 + i] = mnew;
        lS[q0 + i] = lS[q0 + i] * alpha + sum;
      }
    }
    // ---- O += P V^T over c in chunks of 64 ----
    for (int vc = 0; vc < 4; ++vc) {
      __syncthreads();   // Ps/aS ready (vc==0); Vs free (vc>0)
#pragma unroll
      for (int i = 0; i < 4; ++i) {
        const int f = t + 256 * i;
        const int c = f >> 4;
        const int k4 = (f & 15) << 2;
        const float4 v = *(const float4*)(Vp + (size_t)(vc * 64 + c) * NSP + kt + k4);
        Vs[c][k4] = v.x; Vs[c][k4 + 1] = v.y; Vs[c][k4 + 2] = v.z; Vs[c][k4 + 3] = v.w;
      }
      __syncthreads();
      const float al0 = aS[2 * pq], al1 = aS[2 * pq + 1];
#pragma unroll
      for (int j = 0; j < 4; ++j) { oacc[vc][0][j] *= al0; oacc[vc][1][j] *= al1; }
#pragma unroll 2
      for (int k = 0; k < KT; ++k) {
        const float p0 = Ps[k][2 * pq];
        const float p1 = Ps[k][2 * pq + 1];
        const float v0 = Vs[4 * pc + 0][k];
        const float v1 = Vs[4 * pc + 1][k];
        const float v2 = Vs[4 * pc + 2][k];
        const float v3 = Vs[4 * pc + 3][k];
        oacc[vc][0][0] += p0 * v0; oacc[vc][0][1] += p0 * v1;
        oacc[vc][0][2] += p0 * v2; oacc[vc][0][3] += p0 * v3;
        oacc[vc][1][0] += p1 * v0; oacc[vc][1][1] += p1 * v1;
        oacc[vc][1][2] += p1 * v2; oacc[vc][1][3] += p1 * v3;
      }
    }
  }
  __syncthreads();
  const float li0 = 1.f / lS[2 * pq];
  const float li1 = 1.f / lS[2 * pq + 1];
#pragma unroll
  for (int vc = 0; vc < 4; ++vc)
#pragma unroll
    for (int j = 0; j < 4; ++j) {
      const int ch = vc * 64 + 4 * pc + j;
      float* op = obuf + ((size_t)(b * CH + ch)) * NSP + qb;
      op[2 * pq] = oacc[vc][0][j] * li0;
      op[2 * pq + 1] = oacc[vc][1][j] * li1;
    }
}

// ---------------- kernel 5: output projection + residual ----------------
__global__ __launch_bounds__(256) void proj_gemm_k(const float* __restrict__ obuf,
                                                   const float* __restrict__ proj_w,
                                                   const float* __restrict__ proj_b,
                                                   const float* __restrict__ x,
                                                   float* __restrict__ out) {
  const int b = blockIdx.z;
  const int ob = blockIdx.y * 64;
  const int nb = blockIdx.x * 64;
  const int t = threadIdx.x;
  __shared__ float As[16][68];
  __shared__ float Bs[16][64];
  float acc[4][4] = {};
  const int to = (t & 15) * 4;
  const int tn = (t >> 4) * 4;
  const float* ib = obuf + (size_t)b * CH * NSP;
  for (int kc = 0; kc < CH; kc += 16) {
    __syncthreads();
    {
      const int o = t >> 2, k4 = (t & 3) * 4;
      const float4 w4 = *(const float4*)(proj_w + (size_t)(ob + o) * CH + kc + k4);
      As[k4 + 0][o] = w4.x; As[k4 + 1][o] = w4.y;
      As[k4 + 2][o] = w4.z; As[k4 + 3][o] = w4.w;
    }
    {
      const int k = t >> 4, n4 = (t & 15) * 4;
      *(float4*)&Bs[k][n4] = *(const float4*)(ib + (size_t)(kc + k) * NSP + nb + n4);
    }
    __syncthreads();
#pragma unroll
    for (int k = 0; k < 16; ++k) {
      const float4 a4 = *(const float4*)&As[k][to];
      const float4 b4 = *(const float4*)&Bs[k][tn];
      const float av[4] = {a4.x, a4.y, a4.z, a4.w};
      const float bv[4] = {b4.x, b4.y, b4.z, b4.w};
#pragma unroll
      for (int i = 0; i < 4; ++i)
#pragma unroll
        for (int j = 0; j < 4; ++j) acc[i][j] += av[i] * bv[j];
    }
  }
#pragma unroll
  for (int i = 0; i < 4; ++i) {
    const int o = ob + to + i;
    const float bias = proj_b[o];
    const size_t row = ((size_t)(b * CH + o)) * NSP + nb + tn;
    const float4 xr = *(const float4*)(x + row);
    float4 r;
    r.x = acc[i][0] + bias + xr.x;
    r.y = acc[i][1] + bias + xr.y;
    r.z = acc[i][2] + bias + xr.z;
    r.w = acc[i][3] + bias + xr.w;
    *(float4*)(out + row) = r;
  }
}

extern "C" void kernel_launch(void* const* d_in, const int* in_sizes, int n_in,
                              void* d_out, int out_size, void* d_ws, size_t ws_size,
                              hipStream_t stream) {
  const float* x      = (const float*)d_in[0];
  const float* gn_w   = (const float*)d_in[1];
  const float* gn_b   = (const float*)d_in[2];
  const float* qkv_w  = (const float*)d_in[3];
  const float* qkv_b  = (const float*)d_in[4];
  const float* proj_w = (const float*)d_in[5];
  const float* proj_b = (const float*)d_in[6];
  float* out = (float*)d_out;

  float* ws     = (float*)d_ws;
  float* qkv    = ws;                       // 12,582,912 floats
  float* obuf   = qkv + (size_t)BATCH * 3 * CH * NSP;   // 4,194,304 floats
  float* stats  = obuf + (size_t)BATCH * CH * NSP;      // 64
  float* ascale = stats + 64;                           // 1024
  float* bias2  = ascale + BATCH * CH;                  // 3072

  gn_stats_k<<<BATCH * NGRP, 256, 0, stream>>>(x, stats);
  fold_k<<<BATCH, 256, 0, stream>>>(gn_w, gn_b, qkv_w, qkv_b, stats, ascale, bias2);
  qkv_gemm_k<<<dim3(NSP / 64, 3 * CH / 64, BATCH), 256, 0, stream>>>(x, qkv_w, ascale, bias2, qkv);
  attn_k<<<dim3(NSP / QT, BATCH), 256, 0, stream>>>(qkv, obuf);
  proj_gemm_k<<<dim3(NSP / 64, CH / 64, BATCH), 256, 0, stream>>>(obuf, proj_w, proj_b, x, out);
}

// Round 3
// 419.172 us; speedup vs baseline: 4.1137x; 4.1137x over previous
//
#include <hip/hip_runtime.h>
#include <math.h>

// Fused GN + self-attention block — round 2: fix xt_k transpose-write overrun
// (round 1 wrote n in [0,256) for a 64-wide tile -> corrupted xbT -> absmax 1468).
// Pipeline:
//   gn_stats  -> per-(b,g) mean/rstd
//   fold_k    -> ascale[b][c] = rstd*gn_w ; bias2[b][o] = qkv_b + W@(gn_b - mean*a)
//                (Q part pre-scaled 1/16) ; wb = bf16(qkv_w, Q rows pre-scaled 1/16)
//   xt_k      -> xbT[b][n][c] = bf16(x[b][c][n] * ascale[b][c])   (LDS transpose)
//   qkv_mfma  -> qT[b][n][c], kT[b][n][c], vN[b][c][n]  (bf16, bias added fp32)
//   attn_mfma -> oT[b][n][c] fp32 (flash, online softmax fp32, MFMA bf16)
//   proj_gemm -> out = x + proj_w @ o + proj_b  (fp32 VALU)

#define BATCH 4
#define CH 256
#define NSP 4096
#define NGRP 8
#define CPG 32

typedef __attribute__((ext_vector_type(8))) short bf16x8;   // 8 bf16 = 4 VGPRs
typedef __attribute__((ext_vector_type(4))) float f32x4;    // MFMA 16x16 accumulator

__device__ __forceinline__ unsigned short f2bf(float f) {
  union { float f; unsigned u; } v; v.f = f;
  unsigned r = v.u + 0x7FFF + ((v.u >> 16) & 1);   // RNE
  return (unsigned short)(r >> 16);
}

// ---------------- kernel 1: GroupNorm statistics ----------------
__global__ __launch_bounds__(256) void gn_stats_k(const float* __restrict__ x,
                                                  float* __restrict__ stats) {
  const int bg = blockIdx.x;  // b*8+g ; group data contiguous 32*4096 floats
  const float4* p = (const float4*)(x + (size_t)bg * CPG * NSP);
  const int t = threadIdx.x;
  float s1 = 0.f, s2 = 0.f;
  for (int i = t; i < CPG * NSP / 4; i += 256) {
    float4 v = p[i];
    s1 += v.x + v.y + v.z + v.w;
    s2 += v.x * v.x + v.y * v.y + v.z * v.z + v.w * v.w;
  }
  __shared__ float r1[256], r2[256];
  r1[t] = s1; r2[t] = s2;
  __syncthreads();
  for (int off = 128; off > 0; off >>= 1) {
    if (t < off) { r1[t] += r1[t + off]; r2[t] += r2[t + off]; }
    __syncthreads();
  }
  if (t == 0) {
    const float inv = 1.f / (float)(CPG * NSP);
    const float mean = r1[0] * inv;
    const float var = r2[0] * inv - mean * mean;
    stats[bg * 2] = mean;
    stats[bg * 2 + 1] = rsqrtf(var + 1e-5f);
  }
}

// ------- kernel 2: fold GN affine into GEMM scale/bias; convert weights -------
__global__ __launch_bounds__(256) void fold_k(const float* __restrict__ gn_w,
                                              const float* __restrict__ gn_b,
                                              const float* __restrict__ qkv_w,
                                              const float* __restrict__ qkv_b,
                                              const float* __restrict__ stats,
                                              float* __restrict__ ascale,
                                              float* __restrict__ bias2,
                                              unsigned short* __restrict__ wb) {
  const int b = blockIdx.x;   // 4 blocks, 256 threads
  const int t = threadIdx.x;
  __shared__ float bb[CH];
  {
    const int c = t;
    const int g = c / CPG;
    const float mean = stats[(b * NGRP + g) * 2];
    const float rstd = stats[(b * NGRP + g) * 2 + 1];
    const float a = rstd * gn_w[c];
    ascale[b * CH + c] = a;
    bb[c] = gn_b[c] - mean * a;
  }
  __syncthreads();
  for (int o = t; o < 3 * CH; o += 256) {
    const float* wrow = qkv_w + (size_t)o * CH;
    float acc = qkv_b[o];
    for (int c = 0; c < CH; ++c) acc += wrow[c] * bb[c];
    if (o < CH) acc *= 0.0625f;             // fold 1/sqrt(C) into q
    bias2[b * 3 * CH + o] = acc;
  }
  // bf16 weight conversion (batch-independent; each block does 192 rows)
  for (int idx = t; idx < 192 * CH; idx += 256) {
    const int row = b * 192 + (idx >> 8);
    const int c = idx & 255;
    float w = qkv_w[(size_t)row * CH + c];
    if (row < CH) w *= 0.0625f;             // Q rows pre-scaled
    wb[(size_t)row * CH + c] = f2bf(w);
  }
}

// ------- kernel 3: x -> xbT[b][n][c] = bf16(x * ascale)  (transpose) -------
__global__ __launch_bounds__(256) void xt_k(const float* __restrict__ x,
                                            const float* __restrict__ ascale,
                                            unsigned short* __restrict__ xbT) {
  const int b = blockIdx.z, cb = blockIdx.y * 64, nb = blockIdx.x * 64;
  const int t = threadIdx.x;
  __shared__ float Ls[64][68];
  for (int i = 0; i < 4; ++i) {
    const int idx = t + i * 256;
    const int c = idx >> 4, n4 = (idx & 15) << 2;
    const float a = ascale[b * CH + cb + c];
    const float4 v = *(const float4*)(x + ((size_t)(b * CH + cb + c)) * NSP + nb + n4);
    Ls[c][n4] = v.x * a; Ls[c][n4 + 1] = v.y * a;
    Ls[c][n4 + 2] = v.z * a; Ls[c][n4 + 3] = v.w * a;
  }
  __syncthreads();
  // write phase: 64 n x 4 cg-groups = 256 items -> EXACTLY one pass of 256 threads
  {
    const int n = t >> 2, cg = (t & 3) << 4;
    unsigned int pk[8];
#pragma unroll
    for (int j = 0; j < 8; ++j) {
      const unsigned short l16 = f2bf(Ls[cg + 2 * j][n]);
      const unsigned short h16 = f2bf(Ls[cg + 2 * j + 1][n]);
      pk[j] = (unsigned)l16 | ((unsigned)h16 << 16);
    }
    unsigned short* dst = xbT + ((size_t)(b * NSP) + nb + n) * CH + cb + cg;
    *(uint4*)dst = *(uint4*)&pk[0];
    *(uint4*)(dst + 8) = *(uint4*)&pk[4];
  }
}

// ------- kernel 4: QKV GEMM, bf16 MFMA -------
// D[o][n] = sum_c wb[o][c] * xbT[n][c] ; +bias2 ; scatter to qT/kT (n-major) and vN (c-major)
__global__ __launch_bounds__(256) void qkv_mfma_k(const unsigned short* __restrict__ wb,
                                                  const unsigned short* __restrict__ xbT,
                                                  const float* __restrict__ bias2,
                                                  unsigned short* __restrict__ qT,
                                                  unsigned short* __restrict__ kT,
                                                  unsigned short* __restrict__ vN) {
  const int b = blockIdx.z, ob = blockIdx.y * 64, nb = blockIdx.x * 64;
  const int t = threadIdx.x;
  __shared__ short Ws[64][264];   // [o][c], +8 pad -> 2-way LDS
  __shared__ short Xs[64][264];   // [n][c]
  for (int i = 0; i < 8; ++i) {
    const int idx = t + i * 256;
    const int row = idx >> 5, u = (idx & 31) << 3;
    *(float4*)&Ws[row][u] = *(const float4*)(wb + ((size_t)(ob + row)) * CH + u);
    *(float4*)&Xs[row][u] = *(const float4*)(xbT + ((size_t)(b * NSP) + nb + row) * CH + u);
  }
  __syncthreads();
  const int lane = t & 63, wave = t >> 6, lo = lane & 15, hi = lane >> 4;
  const f32x4 zero = {0.f, 0.f, 0.f, 0.f};
  f32x4 acc[4] = {zero, zero, zero, zero};
#pragma unroll
  for (int ks = 0; ks < 8; ++ks) {
    const bf16x8 a = *(const bf16x8*)&Ws[wave * 16 + lo][ks * 32 + hi * 8];
#pragma unroll
    for (int nt = 0; nt < 4; ++nt) {
      const bf16x8 xv = *(const bf16x8*)&Xs[nt * 16 + lo][ks * 32 + hi * 8];
      acc[nt] = __builtin_amdgcn_mfma_f32_16x16x32_bf16(a, xv, acc[nt], 0, 0, 0);
    }
  }
#pragma unroll
  for (int nt = 0; nt < 4; ++nt) {
#pragma unroll
    for (int r = 0; r < 4; ++r) {
      const int o = ob + wave * 16 + hi * 4 + r;          // D row
      const int n = nb + nt * 16 + lo;                    // D col
      const float v = acc[nt][r] + bias2[b * 3 * CH + o];
      if (o < CH)            qT[((size_t)(b * NSP) + n) * CH + o] = f2bf(v);
      else if (o < 2 * CH)   kT[((size_t)(b * NSP) + n) * CH + (o - CH)] = f2bf(v);
      else                   vN[((size_t)(b * CH) + (o - 2 * CH)) * NSP + n] = f2bf(v);
    }
  }
}

// ------- kernel 5: flash attention, bf16 MFMA, fp32 online softmax -------
// 512 threads = 8 waves = 4 pairs; pair owns 16 q rows; within pair wave wip
// computes m-half of S and c-half of O. QT=64, KT=64, Q entirely in registers.
__global__ __launch_bounds__(512) void attn_mfma_k(const unsigned short* __restrict__ qT,
                                                   const unsigned short* __restrict__ kT,
                                                   const unsigned short* __restrict__ vN,
                                                   float* __restrict__ oT) {
  const int b = blockIdx.y;
  const int qb = blockIdx.x * 64;
  const int t = threadIdx.x;
  const int wid = t >> 6, lane = t & 63, lo = lane & 15, hi = lane >> 4;
  const int pair = wid >> 1, wip = wid & 1;

  __shared__ short Kt[64][264];       // [m][c]   33792 B
  __shared__ short Vs[256][72];       // [c][m]   36864 B
  __shared__ short Ps[4][16][72];     // per-pair [q][m]  9216 B
  __shared__ float sMax[4][2][16], sSum[4][2][16];

  // Q fragments in registers: rows = pair's 16 q, full C=256 (8 k-steps)
  const int qrow = qb + pair * 16 + lo;
  bf16x8 qreg[8];
#pragma unroll
  for (int ks = 0; ks < 8; ++ks)
    qreg[ks] = *(const bf16x8*)(qT + ((size_t)(b * NSP) + qrow) * CH + ks * 32 + hi * 8);

  float mrun[4] = {-INFINITY, -INFINITY, -INFINITY, -INFINITY};
  float lrun[4] = {0.f, 0.f, 0.f, 0.f};
  const f32x4 zero = {0.f, 0.f, 0.f, 0.f};
  f32x4 oacc[8] = {zero, zero, zero, zero, zero, zero, zero, zero};

  for (int kt = 0; kt < NSP; kt += 64) {
    __syncthreads();   // A: prior tile's LDS reads done before overwrite
#pragma unroll
    for (int i = 0; i < 4; ++i) {     // stage K tile [64][256] bf16
      const int idx = t + i * 512;
      const int row = idx >> 5, u = (idx & 31) << 3;
      *(float4*)&Kt[row][u] =
          *(const float4*)(kT + ((size_t)(b * NSP) + kt + row) * CH + u);
    }
#pragma unroll
    for (int i = 0; i < 4; ++i) {     // stage V tile [256][64] bf16
      const int idx = t + i * 512;
      const int row = idx >> 3, u = (idx & 7) << 3;
      *(float4*)&Vs[row][u] =
          *(const float4*)(vN + ((size_t)(b * CH) + row) * NSP + kt + u);
    }
    __syncthreads();   // B: stage complete

    // S = Q K^T for this wave's m-half (2 m-tiles of 16)
    f32x4 s[2] = {zero, zero};
#pragma unroll
    for (int ks = 0; ks < 8; ++ks) {
#pragma unroll
      for (int mt = 0; mt < 2; ++mt) {
        const bf16x8 kv = *(const bf16x8*)&Kt[wip * 32 + mt * 16 + lo][ks * 32 + hi * 8];
        s[mt] = __builtin_amdgcn_mfma_f32_16x16x32_bf16(qreg[ks], kv, s[mt], 0, 0, 0);
      }
    }

    // per-row (r = hi*4+reg) partial max over this wave's 32 m
    float mx[4];
#pragma unroll
    for (int r = 0; r < 4; ++r) {
      float m_ = fmaxf(s[0][r], s[1][r]);
      m_ = fmaxf(m_, __shfl_xor(m_, 1));
      m_ = fmaxf(m_, __shfl_xor(m_, 2));
      m_ = fmaxf(m_, __shfl_xor(m_, 4));
      m_ = fmaxf(m_, __shfl_xor(m_, 8));
      mx[r] = m_;
    }
    if (lo == 0) {
#pragma unroll
      for (int r = 0; r < 4; ++r) sMax[pair][wip][hi * 4 + r] = mx[r];
    }
    __syncthreads();   // C: both halves' maxima visible

    float alpha[4], psum[4];
#pragma unroll
    for (int r = 0; r < 4; ++r) {
      const float mo = sMax[pair][wip ^ 1][hi * 4 + r];
      const float mm = fmaxf(fmaxf(mx[r], mo), mrun[r]);
      alpha[r] = __expf(mrun[r] - mm);
      mrun[r] = mm;
      const float p0 = __expf(s[0][r] - mm);
      const float p1 = __expf(s[1][r] - mm);
      Ps[pair][hi * 4 + r][wip * 32 + lo] = (short)f2bf(p0);
      Ps[pair][hi * 4 + r][wip * 32 + 16 + lo] = (short)f2bf(p1);
      float ps = p0 + p1;
      ps += __shfl_xor(ps, 1);
      ps += __shfl_xor(ps, 2);
      ps += __shfl_xor(ps, 4);
      ps += __shfl_xor(ps, 8);
      psum[r] = ps;
    }
    if (lo == 0) {
#pragma unroll
      for (int r = 0; r < 4; ++r) sSum[pair][wip][hi * 4 + r] = psum[r];
    }
    __syncthreads();   // D: P tile + partial sums visible
#pragma unroll
    for (int r = 0; r < 4; ++r)
      lrun[r] = lrun[r] * alpha[r] + psum[r] + sSum[pair][wip ^ 1][hi * 4 + r];

    // O rescale + O += P V^T  (this wave's c-half: 8 c-tiles of 16)
#pragma unroll
    for (int ct = 0; ct < 8; ++ct) {
#pragma unroll
      for (int r = 0; r < 4; ++r) oacc[ct][r] *= alpha[r];
    }
#pragma unroll
    for (int ks2 = 0; ks2 < 2; ++ks2) {
      const bf16x8 pa = *(const bf16x8*)&Ps[pair][lo][ks2 * 32 + hi * 8];
#pragma unroll
      for (int ct = 0; ct < 8; ++ct) {
        const bf16x8 vv = *(const bf16x8*)&Vs[wip * 128 + ct * 16 + lo][ks2 * 32 + hi * 8];
        oacc[ct] = __builtin_amdgcn_mfma_f32_16x16x32_bf16(pa, vv, oacc[ct], 0, 0, 0);
      }
    }
  }

  float linv[4];
#pragma unroll
  for (int r = 0; r < 4; ++r) linv[r] = 1.f / lrun[r];
#pragma unroll
  for (int ct = 0; ct < 8; ++ct) {
#pragma unroll
    for (int r = 0; r < 4; ++r) {
      const int n = qb + pair * 16 + hi * 4 + r;       // D row
      const int c = wip * 128 + ct * 16 + lo;          // D col
      oT[((size_t)(b * NSP) + n) * CH + c] = oacc[ct][r] * linv[r];
    }
  }
}

// ------- kernel 6: output projection + residual (fp32 VALU) -------
__global__ __launch_bounds__(256) void proj_gemm_k(const float* __restrict__ oT,
                                                   const float* __restrict__ proj_w,
                                                   const float* __restrict__ proj_b,
                                                   const float* __restrict__ x,
                                                   float* __restrict__ out) {
  const int b = blockIdx.z;
  const int ob = blockIdx.y * 64;
  const int nb = blockIdx.x * 64;
  const int t = threadIdx.x;
  __shared__ float As[16][68];
  __shared__ float Bs[16][64];
  float acc[4][4] = {};
  const int to = (t & 15) * 4;
  const int tn = (t >> 4) * 4;
  for (int kc = 0; kc < CH; kc += 16) {
    __syncthreads();
    {
      const int o = t >> 2, k4 = (t & 3) * 4;
      const float4 w4 = *(const float4*)(proj_w + (size_t)(ob + o) * CH + kc + k4);
      As[k4 + 0][o] = w4.x; As[k4 + 1][o] = w4.y;
      As[k4 + 2][o] = w4.z; As[k4 + 3][o] = w4.w;
    }
    {
      const int n = t & 63, cq = t >> 6;   // transpose-stage from oT[n][c]
      const float4 ov = *(const float4*)(oT + ((size_t)(b * NSP) + nb + n) * CH + kc + cq * 4);
      Bs[cq * 4 + 0][n] = ov.x; Bs[cq * 4 + 1][n] = ov.y;
      Bs[cq * 4 + 2][n] = ov.z; Bs[cq * 4 + 3][n] = ov.w;
    }
    __syncthreads();
#pragma unroll
    for (int k = 0; k < 16; ++k) {
      const float4 a4 = *(const float4*)&As[k][to];
      const float4 b4 = *(const float4*)&Bs[k][tn];
      const float av[4] = {a4.x, a4.y, a4.z, a4.w};
      const float bv[4] = {b4.x, b4.y, b4.z, b4.w};
#pragma unroll
      for (int i = 0; i < 4; ++i)
#pragma unroll
        for (int j = 0; j < 4; ++j) acc[i][j] += av[i] * bv[j];
    }
  }
#pragma unroll
  for (int i = 0; i < 4; ++i) {
    const int o = ob + to + i;
    const float bias = proj_b[o];
    const size_t row = ((size_t)(b * CH + o)) * NSP + nb + tn;
    const float4 xr = *(const float4*)(x + row);
    float4 r;
    r.x = acc[i][0] + bias + xr.x;
    r.y = acc[i][1] + bias + xr.y;
    r.z = acc[i][2] + bias + xr.z;
    r.w = acc[i][3] + bias + xr.w;
    *(float4*)(out + row) = r;
  }
}

extern "C" void kernel_launch(void* const* d_in, const int* in_sizes, int n_in,
                              void* d_out, int out_size, void* d_ws, size_t ws_size,
                              hipStream_t stream) {
  const float* x      = (const float*)d_in[0];
  const float* gn_w   = (const float*)d_in[1];
  const float* gn_b   = (const float*)d_in[2];
  const float* qkv_w  = (const float*)d_in[3];
  const float* qkv_b  = (const float*)d_in[4];
  const float* proj_w = (const float*)d_in[5];
  const float* proj_b = (const float*)d_in[6];
  float* out = (float*)d_out;

  char* w = (char*)d_ws;
  unsigned short* qT  = (unsigned short*)w; w += (size_t)BATCH * NSP * CH * 2;
  unsigned short* kT  = (unsigned short*)w; w += (size_t)BATCH * NSP * CH * 2;
  unsigned short* vN  = (unsigned short*)w; w += (size_t)BATCH * NSP * CH * 2;
  unsigned short* xbT = (unsigned short*)w; w += (size_t)BATCH * NSP * CH * 2;
  unsigned short* wb  = (unsigned short*)w; w += (size_t)3 * CH * CH * 2;
  float* oT     = (float*)w; w += (size_t)BATCH * NSP * CH * 4;
  float* stats  = (float*)w; w += 64 * 4;
  float* ascale = (float*)w; w += BATCH * CH * 4;
  float* bias2  = (float*)w; w += BATCH * 3 * CH * 4;

  gn_stats_k<<<BATCH * NGRP, 256, 0, stream>>>(x, stats);
  fold_k<<<BATCH, 256, 0, stream>>>(gn_w, gn_b, qkv_w, qkv_b, stats, ascale, bias2, wb);
  xt_k<<<dim3(NSP / 64, CH / 64, BATCH), 256, 0, stream>>>(x, ascale, xbT);
  qkv_mfma_k<<<dim3(NSP / 64, 3 * CH / 64, BATCH), 256, 0, stream>>>(wb, xbT, bias2, qT, kT, vN);
  attn_mfma_k<<<dim3(NSP / 64, BATCH), 512, 0, stream>>>(qT, kT, vN, oT);
  proj_gemm_k<<<dim3(NSP / 64, CH / 64, BATCH), 256, 0, stream>>>(oT, proj_w, proj_b, x, out);
}